// Round 8
// baseline (82.355 us; speedup 1.0000x reference)
//
#include <hip/hip_runtime.h>

#define NPTS   65536
#define KNN    8
#define CDIM   64
#define SHB    9
#define NCODES 8192
#define NPHASE 4
#define PSHIFT 11  // 2048 codes/slice -> 2 MB slice fits 4 MB per-XCD L2
#define PTSW   8   // points per wave
#define WAVES  4
#define NBLK   (NPTS / (PTSW * WAVES))   // 2048 blocks -> 8 blocks/CU
#define LSTRIDE 96 // per-point LDS: ids u16[8]@0, wbar f32[8]@16, c f32[8]@48, K@80, sm8@84, mask@88

#define QSTEP    3.0517578125e-05f   // 0.0625 / 2048
#define QINVSTEP 32768.0f

typedef _Float16 half2v __attribute__((ext_vector_type(2)));

static __device__ __forceinline__ unsigned int pk16(float a, float b) {
    union { unsigned int u; _Float16 h[2]; } x;
    x.h[0] = (_Float16)a; x.h[1] = (_Float16)b;
    return x.u;
}
static __device__ __forceinline__ half2v as_h2(unsigned int u) {
    union { unsigned int u; half2v h; } x; x.u = u; return x.h;
}
static __device__ __forceinline__ unsigned int quant12(float v) {
    int q = (int)rintf(v * QINVSTEP) + 2048;
    q = q < 0 ? 0 : (q > 4095 ? 4095 : q);
    return (unsigned int)q;
}

// rec: (8192, 64) x 16 B. Per (code,dim): d0..d2 = s0..s7 as 12-bit biased
// fixed-point (bit offset 12*s), d3 = (s8, code) fp16 pair.
// ONE dwordx4 per neighbor visit (was dwordx4 + dword) -> tests the
// ~16 cyc/wave-load-instruction TA cost model.

__global__ __launch_bounds__(256) void repack_kernel(
    const float* __restrict__ codes,   // (8192,64)
    const float* __restrict__ shc,     // (8192,576)
    unsigned int* __restrict__ rec)    // (8192*256) dwords
{
    const int wid  = threadIdx.x >> 6;
    const int lane = threadIdx.x & 63;   // dim
    const int c    = blockIdx.x * 4 + wid;

    const float* p = shc + (size_t)c * (CDIM * SHB) + lane * SHB;
    float v[SHB];
#pragma unroll
    for (int s = 0; s < SHB; ++s) v[s] = p[s];
    const float cv = codes[c * CDIM + lane];

    unsigned int q[8];
#pragma unroll
    for (int s = 0; s < 8; ++s) q[s] = quant12(v[s]);

    uint4 a;
    a.x = q[0] | (q[1] << 12) | (q[2] << 24);
    a.y = (q[2] >> 8) | (q[3] << 4) | (q[4] << 16) | (q[5] << 28);
    a.z = (q[5] >> 4) | (q[6] << 8) | (q[7] << 20);
    a.w = pk16(v[8], cv);
    *reinterpret_cast<uint4*>(rec + (size_t)c * 256 + 4 * lane) = a;
}

#define CONSUME(Av, Wv, P)                                                     \
    do {                                                                       \
        float aggA = fmaf((float)(Av.x & 0xfffu),                c0, -Kp);     \
        float aggB = fmaf((float)((Av.x >> 12) & 0xfffu),        c1, 0.0f);    \
        aggA = fmaf((float)(((Av.x >> 24) | (Av.y << 8)) & 0xfffu), c2, aggA); \
        aggB = fmaf((float)((Av.y >> 4) & 0xfffu),               c3, aggB);    \
        aggA = fmaf((float)((Av.y >> 16) & 0xfffu),              c4, aggA);    \
        aggB = fmaf((float)(((Av.y >> 28) | (Av.z << 4)) & 0xfffu), c5, aggB); \
        aggA = fmaf((float)((Av.z >> 8) & 0xfffu),               c6, aggA);    \
        aggB = fmaf((float)(Av.z >> 20),                         c7, aggB);    \
        const half2v b2 = as_h2(Av.w);                                         \
        aggA = fmaf((float)b2[0], s8m, aggA);                                  \
        acc_s[P] += Wv * (aggA + aggB);                                        \
        acc_c[P] += Wv * (float)b2[1];                                         \
    } while (0)

__global__ __launch_bounds__(256) void shcode_phased5(
    const float* __restrict__ qp,
    const float* __restrict__ vd,
    const float* __restrict__ cpos,
    const unsigned int* __restrict__ rec,
    const int*   __restrict__ knn,
    float* __restrict__ out)
{
    __shared__ unsigned char lds[WAVES * PTSW * LSTRIDE];   // 3 KB

    const int tid   = threadIdx.x;
    const int lane  = tid & 63;
    const int wid   = tid >> 6;
    const int pbase = (blockIdx.x * WAVES + wid) * PTSW;

    // ---- precompute: lane l (< PTSW) owns point pbase+l ----
    if (lane < PTSW) {
        const int n = pbase + lane;
        unsigned char* pr = lds + (wid * PTSW + lane) * LSTRIDE;
        unsigned short* ids16 = (unsigned short*)(pr + 0);
        float*          wbar  = (float*)(pr + 16);
        float*          cf    = (float*)(pr + 48);
        float*          Kpp   = (float*)(pr + 80);
        float*          sm8p  = (float*)(pr + 84);
        unsigned int*   maskp = (unsigned int*)(pr + 88);

        const float qx = qp[n * 3 + 0];
        const float qy = qp[n * 3 + 1];
        const float qz = qp[n * 3 + 2];

        int   ids[KNN];
        float w[KNN];
        float wsum = 0.0f;
#pragma unroll
        for (int k = 0; k < KNN; ++k) {
            const int id = knn[n * KNN + k];
            ids[k] = id;
            const float dx = qx - cpos[id * 3 + 0];
            const float dy = qy - cpos[id * 3 + 1];
            const float dz = qz - cpos[id * 3 + 2];
            w[k] = 1.0f / (dx * dx + dy * dy + dz * dz + 1e-16f);
            wsum += w[k];
        }
        const float inv = 1.0f / wsum;
        unsigned int mask = 0u;
#pragma unroll
        for (int k = 0; k < KNN; ++k) {
            ids16[k] = (unsigned short)ids[k];
            wbar[k]  = w[k] * inv;
            mask |= 1u << (((unsigned)ids[k] >> PSHIFT) * 8 + k);
        }
        *maskp = mask;

        const float x = vd[n * 3 + 0];
        const float y = vd[n * 3 + 1];
        const float z = vd[n * 3 + 2];
        const float xx = x * x, yy = y * y, zz = z * z;
        float sm[8];
        sm[0] = 0.28209479177387814f;
        sm[1] = -0.4886025119029199f * y;
        sm[2] =  0.4886025119029199f * z;
        sm[3] = -0.4886025119029199f * x;
        sm[4] =  1.0925484305920792f * (x * y);
        sm[5] = -1.0925484305920792f * (y * z);
        sm[6] =  0.31539156525252005f * (2.0f * zz - xx - yy);
        sm[7] = -1.0925484305920792f * (x * z);
        float ssum = 0.0f;
#pragma unroll
        for (int s = 0; s < 8; ++s) { cf[s] = sm[s] * QSTEP; ssum += sm[s]; }
        *Kpp  = 2048.0f * QSTEP * ssum;
        *sm8p = 0.5462742152960396f * (xx - yy);
    }
    __syncthreads();

    float acc_c[PTSW], acc_s[PTSW];
#pragma unroll
    for (int p = 0; p < PTSW; ++p) { acc_c[p] = 0.0f; acc_s[p] = 0.0f; }

    for (int ph = 0; ph < NPHASE; ++ph) {
        // batch-prefetch all point masks for this phase
        unsigned int pm[PTSW];
#pragma unroll
        for (int p = 0; p < PTSW; ++p)
            pm[p] = *(const unsigned int*)(lds + (wid * PTSW + p) * LSTRIDE + 88);

#pragma unroll
        for (int p = 0; p < PTSW; ++p) {
            unsigned int m8 =
                ((unsigned int)__builtin_amdgcn_readfirstlane((int)pm[p])
                 >> (8 * ph)) & 0xffu;
            if (!m8) continue;                      // uniform scalar branch

            const unsigned char* pr = lds + (wid * PTSW + p) * LSTRIDE;
            const unsigned short* ids16 = (const unsigned short*)pr;
            const float* wbar = (const float*)(pr + 16);
            const float* cfp  = (const float*)(pr + 48);
            const float c0 = cfp[0], c1 = cfp[1], c2 = cfp[2], c3 = cfp[3];
            const float c4 = cfp[4], c5 = cfp[5], c6 = cfp[6], c7 = cfp[7];
            const float Kp  = *(const float*)(pr + 80);
            const float s8m = *(const float*)(pr + 84);

            // ---- 2-deep software pipeline over set bits ----
            int k = __builtin_ctz(m8); m8 &= m8 - 1u;
            int id0 = __builtin_amdgcn_readfirstlane((int)ids16[k]);
            float w0 = wbar[k];
            uint4 A0 = *reinterpret_cast<const uint4*>(
                rec + (size_t)id0 * 256 + 4 * lane);

            while (m8) {
                k = __builtin_ctz(m8); m8 &= m8 - 1u;
                const int id1 = __builtin_amdgcn_readfirstlane((int)ids16[k]);
                const float w1 = wbar[k];
                const uint4 A1 = *reinterpret_cast<const uint4*>(
                    rec + (size_t)id1 * 256 + 4 * lane);   // issue before consuming A0
                CONSUME(A0, w0, p);
                A0 = A1; w0 = w1;
            }
            CONSUME(A0, w0, p);
        }
        __syncthreads();   // keep block's waves phase-aligned
    }

#pragma unroll
    for (int p = 0; p < PTSW; ++p) {
        const int n = pbase + p;
        __builtin_nontemporal_store(acc_c[p], &out[n * CDIM + lane]);
        __builtin_nontemporal_store(acc_s[p],
                                    &out[(size_t)NPTS * CDIM + n * CDIM + lane]);
    }
}

// --- fallback (round-1 fp32 direct-gather) if workspace too small ---
__global__ __launch_bounds__(256) void shcode_kernel(
    const float* __restrict__ qp, const float* __restrict__ vd,
    const float* __restrict__ cpos, const float* __restrict__ codes,
    const float* __restrict__ shc, const int* __restrict__ knn,
    float* __restrict__ out)
{
    const int wid  = threadIdx.x >> 6;
    const int lane = threadIdx.x & 63;
    const int n    = blockIdx.x * 4 + wid;

    const float x = vd[n * 3 + 0], y = vd[n * 3 + 1], z = vd[n * 3 + 2];
    const float xx = x * x, yy = y * y, zz = z * z;
    const float sm0 = 0.28209479177387814f;
    const float sm1 = -0.4886025119029199f * y;
    const float sm2 =  0.4886025119029199f * z;
    const float sm3 = -0.4886025119029199f * x;
    const float sm4 =  1.0925484305920792f * (x * y);
    const float sm5 = -1.0925484305920792f * (y * z);
    const float sm6 =  0.31539156525252005f * (2.0f * zz - xx - yy);
    const float sm7 = -1.0925484305920792f * (x * z);
    const float sm8 =  0.5462742152960396f * (xx - yy);

    const float qx = qp[n * 3 + 0], qy = qp[n * 3 + 1], qz = qp[n * 3 + 2];

    int idx[KNN]; float w[KNN]; float wsum = 0.0f;
#pragma unroll
    for (int k = 0; k < KNN; ++k) {
        int id = __builtin_amdgcn_readfirstlane(knn[n * KNN + k]);
        idx[k] = id;
        const float dx = qx - cpos[id * 3 + 0];
        const float dy = qy - cpos[id * 3 + 1];
        const float dz = qz - cpos[id * 3 + 2];
        const float sd = dx * dx + dy * dy + dz * dz + 1e-16f;
        w[k] = 1.0f / sd; wsum += w[k];
    }
    const float winv = 1.0f / wsum;

    float acc_c = 0.0f, acc_s = 0.0f;
#pragma unroll
    for (int k = 0; k < KNN; ++k) {
        const float wk = w[k] * winv;
        acc_c += wk * codes[(size_t)idx[k] * CDIM + lane];
        const float* p = shc + (size_t)idx[k] * (CDIM * SHB) + lane * SHB;
        acc_s += wk * (sm0 * p[0] + sm1 * p[1] + sm2 * p[2]
                     + sm3 * p[3] + sm4 * p[4] + sm5 * p[5]
                     + sm6 * p[6] + sm7 * p[7] + sm8 * p[8]);
    }
    out[n * CDIM + lane] = acc_c;
    out[(size_t)NPTS * CDIM + n * CDIM + lane] = acc_s;
}

extern "C" void kernel_launch(void* const* d_in, const int* in_sizes, int n_in,
                              void* d_out, int out_size, void* d_ws, size_t ws_size,
                              hipStream_t stream) {
    const float* qp    = (const float*)d_in[0];
    const float* vd    = (const float*)d_in[1];
    const float* cpos  = (const float*)d_in[2];
    const float* codes = (const float*)d_in[3];
    const float* shc   = (const float*)d_in[4];
    const int*   knn   = (const int*)d_in[6];
    float* out = (float*)d_out;

    const size_t rec_bytes = (size_t)NCODES * 256 * 4;  // 8 MB

    if (ws_size >= rec_bytes) {
        unsigned int* rec = (unsigned int*)d_ws;
        hipLaunchKernelGGL(repack_kernel, dim3(NCODES / 4), dim3(256), 0, stream,
                           codes, shc, rec);
        hipLaunchKernelGGL(shcode_phased5, dim3(NBLK), dim3(256), 0, stream,
                           qp, vd, cpos, rec, knn, out);
    } else {
        hipLaunchKernelGGL(shcode_kernel, dim3(NPTS / 4), dim3(256), 0, stream,
                           qp, vd, cpos, codes, shc, knn, out);
    }
}

// Round 9
// 75.335 us; speedup vs baseline: 1.0932x; 1.0932x over previous
//
#include <hip/hip_runtime.h>

#define NPTS   65536
#define KNN    8
#define CDIM   64
#define SHB    9
#define NCODES 8192

typedef _Float16 half2v __attribute__((ext_vector_type(2)));

static __device__ __forceinline__ unsigned int pk16(float a, float b) {
    union { unsigned int u; _Float16 h[2]; } x;
    x.h[0] = (_Float16)a; x.h[1] = (_Float16)b;
    return x.u;
}
static __device__ __forceinline__ half2v as_h2(unsigned int u) {
    union { unsigned int u; half2v h; } x; x.u = u; return x.h;
}

#if defined(__has_builtin)
#if __has_builtin(__builtin_amdgcn_fdot2)
#define HAS_FDOT2 1
#endif
#endif

// recA: (8192, 64dims) x 16 B -> (s0,s1)(s2,s3)(s4,s5)(s6,s7) fp16 pairs,
//       lane-contiguous (wave reads one code's row as a 1024 B burst).
// recB: (8192, 64dims) x  4 B -> (s8, code) fp16 pair.

__global__ __launch_bounds__(256) void repack_kernel(
    const float* __restrict__ codes,   // (8192,64)
    const float* __restrict__ shc,     // (8192,576)
    unsigned int* __restrict__ recA,   // 8192*256 dwords (8 MB)
    unsigned int* __restrict__ recB)   // 8192*64 dwords (2 MB)
{
    const int wid  = threadIdx.x >> 6;
    const int lane = threadIdx.x & 63;   // dim
    const int c    = blockIdx.x * 4 + wid;

    const float* p = shc + (size_t)c * (CDIM * SHB) + lane * SHB;
    float v[SHB];
#pragma unroll
    for (int s = 0; s < SHB; ++s) v[s] = p[s];
    const float cv = codes[c * CDIM + lane];

    uint4 a;
    a.x = pk16(v[0], v[1]);
    a.y = pk16(v[2], v[3]);
    a.z = pk16(v[4], v[5]);
    a.w = pk16(v[6], v[7]);
    *reinterpret_cast<uint4*>(recA + (size_t)c * 256 + 4 * lane) = a;
    recB[(size_t)c * 64 + lane] = pk16(v[8], cv);
}

// Flat gather kernel: one wave per point. All 16 gather loads issue
// unconditionally back-to-back (max MLP, no serial visit chain, no LDS,
// no barriers); weights + SH basis compute under the load shadow.
__global__ __launch_bounds__(256) void shcode_flat(
    const float* __restrict__ qp,
    const float* __restrict__ vd,
    const float* __restrict__ cpos,
    const unsigned int* __restrict__ recA,
    const unsigned int* __restrict__ recB,
    const int*   __restrict__ knn,
    float* __restrict__ out)
{
    const int wid  = threadIdx.x >> 6;
    const int lane = threadIdx.x & 63;
    const int n    = blockIdx.x * 4 + wid;

    // neighbor ids -> SGPRs (wave-uniform)
    int id[KNN];
#pragma unroll
    for (int k = 0; k < KNN; ++k)
        id[k] = __builtin_amdgcn_readfirstlane(knn[n * KNN + k]);

    // ---- issue ALL gathers up-front ----
    uint4        A[KNN];
    unsigned int B[KNN];
#pragma unroll
    for (int k = 0; k < KNN; ++k) {
        A[k] = *reinterpret_cast<const uint4*>(recA + (size_t)id[k] * 256 + 4 * lane);
        B[k] = recB[(size_t)id[k] * 64 + lane];
    }

    // ---- weights + SH basis under the load shadow ----
    const float qx = qp[n * 3 + 0];
    const float qy = qp[n * 3 + 1];
    const float qz = qp[n * 3 + 2];

    float w[KNN];
    float wsum = 0.0f;
#pragma unroll
    for (int k = 0; k < KNN; ++k) {
        const float dx = qx - cpos[id[k] * 3 + 0];
        const float dy = qy - cpos[id[k] * 3 + 1];
        const float dz = qz - cpos[id[k] * 3 + 2];
        w[k] = 1.0f / (dx * dx + dy * dy + dz * dz + 1e-16f);
        wsum += w[k];
    }
    const float winv = 1.0f / wsum;

    const float x = vd[n * 3 + 0];
    const float y = vd[n * 3 + 1];
    const float z = vd[n * 3 + 2];
    const float xx = x * x, yy = y * y, zz = z * z;
    const half2v smh0 = as_h2(pk16(0.28209479177387814f,
                                   -0.4886025119029199f * y));
    const half2v smh1 = as_h2(pk16(0.4886025119029199f * z,
                                   -0.4886025119029199f * x));
    const half2v smh2 = as_h2(pk16(1.0925484305920792f * (x * y),
                                   -1.0925484305920792f * (y * z)));
    const half2v smh3 = as_h2(pk16(0.31539156525252005f * (2.0f * zz - xx - yy),
                                   -1.0925484305920792f * (x * z)));
    const float sm8f = 0.5462742152960396f * (xx - yy);

    // ---- consume ----
    float acc_c = 0.0f, acc_s = 0.0f;
#pragma unroll
    for (int k = 0; k < KNN; ++k) {
        const float wk = w[k] * winv;
        const half2v b2 = as_h2(B[k]);
#ifdef HAS_FDOT2
        float agg = sm8f * (float)b2[0];
        agg = __builtin_amdgcn_fdot2(as_h2(A[k].w), smh3, agg, false);
        agg = __builtin_amdgcn_fdot2(as_h2(A[k].z), smh2, agg, false);
        agg = __builtin_amdgcn_fdot2(as_h2(A[k].y), smh1, agg, false);
        agg = __builtin_amdgcn_fdot2(as_h2(A[k].x), smh0, agg, false);
#else
        const half2v a0 = as_h2(A[k].x), a1 = as_h2(A[k].y);
        const half2v a2 = as_h2(A[k].z), a3 = as_h2(A[k].w);
        float agg = sm8f * (float)b2[0];
        agg += (float)a0[0] * (float)smh0[0] + (float)a0[1] * (float)smh0[1];
        agg += (float)a1[0] * (float)smh1[0] + (float)a1[1] * (float)smh1[1];
        agg += (float)a2[0] * (float)smh2[0] + (float)a2[1] * (float)smh2[1];
        agg += (float)a3[0] * (float)smh3[0] + (float)a3[1] * (float)smh3[1];
#endif
        acc_s += wk * agg;
        acc_c += wk * (float)b2[1];
    }

    __builtin_nontemporal_store(acc_c, &out[n * CDIM + lane]);
    __builtin_nontemporal_store(acc_s, &out[(size_t)NPTS * CDIM + n * CDIM + lane]);
}

// --- fallback (round-1 fp32 direct-gather) if workspace too small ---
__global__ __launch_bounds__(256) void shcode_kernel(
    const float* __restrict__ qp, const float* __restrict__ vd,
    const float* __restrict__ cpos, const float* __restrict__ codes,
    const float* __restrict__ shc, const int* __restrict__ knn,
    float* __restrict__ out)
{
    const int wid  = threadIdx.x >> 6;
    const int lane = threadIdx.x & 63;
    const int n    = blockIdx.x * 4 + wid;

    const float x = vd[n * 3 + 0], y = vd[n * 3 + 1], z = vd[n * 3 + 2];
    const float xx = x * x, yy = y * y, zz = z * z;
    const float sm0 = 0.28209479177387814f;
    const float sm1 = -0.4886025119029199f * y;
    const float sm2 =  0.4886025119029199f * z;
    const float sm3 = -0.4886025119029199f * x;
    const float sm4 =  1.0925484305920792f * (x * y);
    const float sm5 = -1.0925484305920792f * (y * z);
    const float sm6 =  0.31539156525252005f * (2.0f * zz - xx - yy);
    const float sm7 = -1.0925484305920792f * (x * z);
    const float sm8 =  0.5462742152960396f * (xx - yy);

    const float qx = qp[n * 3 + 0], qy = qp[n * 3 + 1], qz = qp[n * 3 + 2];

    int idx[KNN]; float w[KNN]; float wsum = 0.0f;
#pragma unroll
    for (int k = 0; k < KNN; ++k) {
        int id = __builtin_amdgcn_readfirstlane(knn[n * KNN + k]);
        idx[k] = id;
        const float dx = qx - cpos[id * 3 + 0];
        const float dy = qy - cpos[id * 3 + 1];
        const float dz = qz - cpos[id * 3 + 2];
        const float sd = dx * dx + dy * dy + dz * dz + 1e-16f;
        w[k] = 1.0f / sd; wsum += w[k];
    }
    const float winv = 1.0f / wsum;

    float acc_c = 0.0f, acc_s = 0.0f;
#pragma unroll
    for (int k = 0; k < KNN; ++k) {
        const float wk = w[k] * winv;
        acc_c += wk * codes[(size_t)idx[k] * CDIM + lane];
        const float* p = shc + (size_t)idx[k] * (CDIM * SHB) + lane * SHB;
        acc_s += wk * (sm0 * p[0] + sm1 * p[1] + sm2 * p[2]
                     + sm3 * p[3] + sm4 * p[4] + sm5 * p[5]
                     + sm6 * p[6] + sm7 * p[7] + sm8 * p[8]);
    }
    out[n * CDIM + lane] = acc_c;
    out[(size_t)NPTS * CDIM + n * CDIM + lane] = acc_s;
}

extern "C" void kernel_launch(void* const* d_in, const int* in_sizes, int n_in,
                              void* d_out, int out_size, void* d_ws, size_t ws_size,
                              hipStream_t stream) {
    const float* qp    = (const float*)d_in[0];
    const float* vd    = (const float*)d_in[1];
    const float* cpos  = (const float*)d_in[2];
    const float* codes = (const float*)d_in[3];
    const float* shc   = (const float*)d_in[4];
    const int*   knn   = (const int*)d_in[6];
    float* out = (float*)d_out;

    const size_t recA_bytes = (size_t)NCODES * 256 * 4;  // 8 MB
    const size_t recB_bytes = (size_t)NCODES * 64 * 4;   // 2 MB

    if (ws_size >= recA_bytes + recB_bytes) {
        unsigned int* recA = (unsigned int*)d_ws;
        unsigned int* recB = (unsigned int*)((char*)d_ws + recA_bytes);
        hipLaunchKernelGGL(repack_kernel, dim3(NCODES / 4), dim3(256), 0, stream,
                           codes, shc, recA, recB);
        hipLaunchKernelGGL(shcode_flat, dim3(NPTS / 4), dim3(256), 0, stream,
                           qp, vd, cpos, recA, recB, knn, out);
    } else {
        hipLaunchKernelGGL(shcode_kernel, dim3(NPTS / 4), dim3(256), 0, stream,
                           qp, vd, cpos, codes, shc, knn, out);
    }
}

// Round 10
// 57.786 us; speedup vs baseline: 1.4252x; 1.3037x over previous
//
#include <hip/hip_runtime.h>

#define NPTS   65536
#define KNN    8
#define CDIM   64
#define SHB    9
#define NCODES 8192
#define NPHASE 4
#define PSHIFT 11  // 2048 codes/slice -> 2.6 MB slice fits 4 MB per-XCD L2
#define PTSW   8   // points per wave
#define WAVES  4
#define NBLK   (NPTS / (PTSW * WAVES))   // 2048 blocks -> 8 blocks/CU
#define LSTRIDE 80 // per-point LDS: ids u16[8]@0, wbar f32[8]@16, smh u32[4]@48, sm8 f32@64, mask u32@68

typedef _Float16 half2v __attribute__((ext_vector_type(2)));

static __device__ __forceinline__ unsigned int pk16(float a, float b) {
    union { unsigned int u; _Float16 h[2]; } x;
    x.h[0] = (_Float16)a; x.h[1] = (_Float16)b;
    return x.u;
}
static __device__ __forceinline__ half2v as_h2(unsigned int u) {
    union { unsigned int u; half2v h; } x; x.u = u; return x.h;
}

#if defined(__has_builtin)
#if __has_builtin(__builtin_amdgcn_fdot2)
#define HAS_FDOT2 1
#endif
#endif

// recA: (8192, 64dims) x 16 B -> (s0,s1)(s2,s3)(s4,s5)(s6,s7) fp16 pairs.
// recB: (8192, 64dims) x  4 B -> (s8, code) fp16 pair.

__global__ __launch_bounds__(256) void repack_kernel(
    const float* __restrict__ codes,   // (8192,64)
    const float* __restrict__ shc,     // (8192,576)
    unsigned int* __restrict__ recA,   // 8192*256 dwords (8 MB)
    unsigned int* __restrict__ recB)   // 8192*64 dwords (2 MB)
{
    const int wid  = threadIdx.x >> 6;
    const int lane = threadIdx.x & 63;   // dim
    const int c    = blockIdx.x * 4 + wid;

    const float* p = shc + (size_t)c * (CDIM * SHB) + lane * SHB;
    float v[SHB];
#pragma unroll
    for (int s = 0; s < SHB; ++s) v[s] = p[s];
    const float cv = codes[c * CDIM + lane];

    uint4 a;
    a.x = pk16(v[0], v[1]);
    a.y = pk16(v[2], v[3]);
    a.z = pk16(v[4], v[5]);
    a.w = pk16(v[6], v[7]);
    *reinterpret_cast<uint4*>(recA + (size_t)c * 256 + 4 * lane) = a;
    recB[(size_t)c * 64 + lane] = pk16(v[8], cv);
}

static __device__ __forceinline__ void consume_v(
    const uint4 A, unsigned int B, float wk,
    half2v sh0, half2v sh1, half2v sh2, half2v sh3, float s8,
    float& acc_s, float& acc_c)
{
    const half2v b2 = as_h2(B);
#ifdef HAS_FDOT2
    float agg = s8 * (float)b2[0];
    agg = __builtin_amdgcn_fdot2(as_h2(A.w), sh3, agg, false);
    agg = __builtin_amdgcn_fdot2(as_h2(A.z), sh2, agg, false);
    agg = __builtin_amdgcn_fdot2(as_h2(A.y), sh1, agg, false);
    agg = __builtin_amdgcn_fdot2(as_h2(A.x), sh0, agg, false);
#else
    const half2v a0 = as_h2(A.x), a1 = as_h2(A.y);
    const half2v a2 = as_h2(A.z), a3 = as_h2(A.w);
    float agg = s8 * (float)b2[0];
    agg += (float)a0[0] * (float)sh0[0] + (float)a0[1] * (float)sh0[1];
    agg += (float)a1[0] * (float)sh1[0] + (float)a1[1] * (float)sh1[1];
    agg += (float)a2[0] * (float)sh2[0] + (float)a2[1] * (float)sh2[1];
    agg += (float)a3[0] * (float)sh3[0] + (float)a3[1] * (float)sh3[1];
#endif
    acc_s += wk * agg;
    acc_c += wk * (float)b2[1];
}

// Phased gather kernel, dual-stream + 1-ahead pipelined visits.
// Two points' visit streams interleave (one's load latency hides under the
// other's consume) and each stream prefetches its next visit's loads before
// consuming the current one. All state is plain scalar variables under
// wave-uniform branches -> no predicated-array demotion (R7 lesson).
__global__ __launch_bounds__(256) void shcode_phased6(
    const float* __restrict__ qp,
    const float* __restrict__ vd,
    const float* __restrict__ cpos,
    const unsigned int* __restrict__ recA,
    const unsigned int* __restrict__ recB,
    const int*   __restrict__ knn,
    float* __restrict__ out)
{
    __shared__ unsigned char lds[WAVES * PTSW * LSTRIDE];   // 2560 B

    const int tid   = threadIdx.x;
    const int lane  = tid & 63;
    const int wid   = tid >> 6;
    const int pbase = (blockIdx.x * WAVES + wid) * PTSW;

    // ---- precompute: lane l (< PTSW) owns point pbase+l ----
    if (lane < PTSW) {
        const int n = pbase + lane;
        unsigned char* pr = lds + (wid * PTSW + lane) * LSTRIDE;
        unsigned short* ids16 = (unsigned short*)(pr + 0);
        float*          wbar  = (float*)(pr + 16);
        unsigned int*   smh   = (unsigned int*)(pr + 48);
        float*          sm8p  = (float*)(pr + 64);
        unsigned int*   maskp = (unsigned int*)(pr + 68);

        const float qx = qp[n * 3 + 0];
        const float qy = qp[n * 3 + 1];
        const float qz = qp[n * 3 + 2];

        int   ids[KNN];
        float w[KNN];
        float wsum = 0.0f;
#pragma unroll
        for (int k = 0; k < KNN; ++k) {
            const int id = knn[n * KNN + k];
            ids[k] = id;
            const float dx = qx - cpos[id * 3 + 0];
            const float dy = qy - cpos[id * 3 + 1];
            const float dz = qz - cpos[id * 3 + 2];
            w[k] = 1.0f / (dx * dx + dy * dy + dz * dz + 1e-16f);
            wsum += w[k];
        }
        const float inv = 1.0f / wsum;
        unsigned int mask = 0u;
#pragma unroll
        for (int k = 0; k < KNN; ++k) {
            ids16[k] = (unsigned short)ids[k];
            wbar[k]  = w[k] * inv;
            mask |= 1u << (((unsigned)ids[k] >> PSHIFT) * 8 + k);
        }
        *maskp = mask;

        const float x = vd[n * 3 + 0];
        const float y = vd[n * 3 + 1];
        const float z = vd[n * 3 + 2];
        const float xx = x * x, yy = y * y, zz = z * z;
        smh[0] = pk16(0.28209479177387814f,           -0.4886025119029199f * y);
        smh[1] = pk16(0.4886025119029199f * z,        -0.4886025119029199f * x);
        smh[2] = pk16(1.0925484305920792f * (x * y),  -1.0925484305920792f * (y * z));
        smh[3] = pk16(0.31539156525252005f * (2.0f * zz - xx - yy),
                      -1.0925484305920792f * (x * z));
        *sm8p  = 0.5462742152960396f * (xx - yy);
    }
    __syncthreads();

    float acc_c[PTSW], acc_s[PTSW];
#pragma unroll
    for (int p = 0; p < PTSW; ++p) { acc_c[p] = 0.0f; acc_s[p] = 0.0f; }

    for (int ph = 0; ph < NPHASE; ++ph) {
#pragma unroll
        for (int pi = 0; pi < PTSW / 2; ++pi) {
            const int pA = 2 * pi, pB = 2 * pi + 1;
            const unsigned char* prA = lds + (wid * PTSW + pA) * LSTRIDE;
            const unsigned char* prB = lds + (wid * PTSW + pB) * LSTRIDE;

            unsigned int mA =
                ((unsigned int)__builtin_amdgcn_readfirstlane(
                     (int)*(const unsigned int*)(prA + 68)) >> (8 * ph)) & 0xffu;
            unsigned int mB =
                ((unsigned int)__builtin_amdgcn_readfirstlane(
                     (int)*(const unsigned int*)(prB + 68)) >> (8 * ph)) & 0xffu;
            if (!(mA | mB)) continue;               // uniform scalar branch

            const unsigned short* idsA = (const unsigned short*)prA;
            const unsigned short* idsB = (const unsigned short*)prB;
            const float* wbA = (const float*)(prA + 16);
            const float* wbB = (const float*)(prB + 16);
            const unsigned int* suA = (const unsigned int*)(prA + 48);
            const unsigned int* suB = (const unsigned int*)(prB + 48);
            const half2v a_sh0 = as_h2(suA[0]), a_sh1 = as_h2(suA[1]);
            const half2v a_sh2 = as_h2(suA[2]), a_sh3 = as_h2(suA[3]);
            const half2v b_sh0 = as_h2(suB[0]), b_sh1 = as_h2(suB[1]);
            const half2v b_sh2 = as_h2(suB[2]), b_sh3 = as_h2(suB[3]);
            const float a_s8 = *(const float*)(prA + 64);
            const float b_s8 = *(const float*)(prB + 64);

            // ---- prime both streams ----
            uint4 Aa, Ab; unsigned int Ba, Bb; float wa, wb;
            bool hasA = (mA != 0), hasB = (mB != 0);
            if (hasA) {
                const int k = __builtin_ctz(mA); mA &= mA - 1u;
                const int id = __builtin_amdgcn_readfirstlane((int)idsA[k]);
                wa = wbA[k];
                Aa = *reinterpret_cast<const uint4*>(recA + (size_t)id * 256 + 4 * lane);
                Ba = recB[(size_t)id * 64 + lane];
            }
            if (hasB) {
                const int k = __builtin_ctz(mB); mB &= mB - 1u;
                const int id = __builtin_amdgcn_readfirstlane((int)idsB[k]);
                wb = wbB[k];
                Ab = *reinterpret_cast<const uint4*>(recA + (size_t)id * 256 + 4 * lane);
                Bb = recB[(size_t)id * 64 + lane];
            }

            // ---- interleaved, 1-ahead pipelined main loop ----
            while (hasA | hasB) {
                if (hasA) {
                    const uint4 Ac = Aa; const unsigned int Bc = Ba; const float wc = wa;
                    hasA = (mA != 0);
                    if (hasA) {          // issue next-A before consuming current-A
                        const int k = __builtin_ctz(mA); mA &= mA - 1u;
                        const int id = __builtin_amdgcn_readfirstlane((int)idsA[k]);
                        wa = wbA[k];
                        Aa = *reinterpret_cast<const uint4*>(recA + (size_t)id * 256 + 4 * lane);
                        Ba = recB[(size_t)id * 64 + lane];
                    }
                    consume_v(Ac, Bc, wc, a_sh0, a_sh1, a_sh2, a_sh3, a_s8,
                              acc_s[pA], acc_c[pA]);
                }
                if (hasB) {
                    const uint4 Ac = Ab; const unsigned int Bc = Bb; const float wc = wb;
                    hasB = (mB != 0);
                    if (hasB) {          // issue next-B before consuming current-B
                        const int k = __builtin_ctz(mB); mB &= mB - 1u;
                        const int id = __builtin_amdgcn_readfirstlane((int)idsB[k]);
                        wb = wbB[k];
                        Ab = *reinterpret_cast<const uint4*>(recA + (size_t)id * 256 + 4 * lane);
                        Bb = recB[(size_t)id * 64 + lane];
                    }
                    consume_v(Ac, Bc, wc, b_sh0, b_sh1, b_sh2, b_sh3, b_s8,
                              acc_s[pB], acc_c[pB]);
                }
            }
        }
        __syncthreads();   // keep block's waves phase-aligned
    }

#pragma unroll
    for (int p = 0; p < PTSW; ++p) {
        const int n = pbase + p;
        __builtin_nontemporal_store(acc_c[p], &out[n * CDIM + lane]);
        __builtin_nontemporal_store(acc_s[p],
                                    &out[(size_t)NPTS * CDIM + n * CDIM + lane]);
    }
}

// --- fallback (round-1 fp32 direct-gather) if workspace too small ---
__global__ __launch_bounds__(256) void shcode_kernel(
    const float* __restrict__ qp, const float* __restrict__ vd,
    const float* __restrict__ cpos, const float* __restrict__ codes,
    const float* __restrict__ shc, const int* __restrict__ knn,
    float* __restrict__ out)
{
    const int wid  = threadIdx.x >> 6;
    const int lane = threadIdx.x & 63;
    const int n    = blockIdx.x * 4 + wid;

    const float x = vd[n * 3 + 0], y = vd[n * 3 + 1], z = vd[n * 3 + 2];
    const float xx = x * x, yy = y * y, zz = z * z;
    const float sm0 = 0.28209479177387814f;
    const float sm1 = -0.4886025119029199f * y;
    const float sm2 =  0.4886025119029199f * z;
    const float sm3 = -0.4886025119029199f * x;
    const float sm4 =  1.0925484305920792f * (x * y);
    const float sm5 = -1.0925484305920792f * (y * z);
    const float sm6 =  0.31539156525252005f * (2.0f * zz - xx - yy);
    const float sm7 = -1.0925484305920792f * (x * z);
    const float sm8 =  0.5462742152960396f * (xx - yy);

    const float qx = qp[n * 3 + 0], qy = qp[n * 3 + 1], qz = qp[n * 3 + 2];

    int idx[KNN]; float w[KNN]; float wsum = 0.0f;
#pragma unroll
    for (int k = 0; k < KNN; ++k) {
        int id = __builtin_amdgcn_readfirstlane(knn[n * KNN + k]);
        idx[k] = id;
        const float dx = qx - cpos[id * 3 + 0];
        const float dy = qy - cpos[id * 3 + 1];
        const float dz = qz - cpos[id * 3 + 2];
        const float sd = dx * dx + dy * dy + dz * dz + 1e-16f;
        w[k] = 1.0f / sd; wsum += w[k];
    }
    const float winv = 1.0f / wsum;

    float acc_c = 0.0f, acc_s = 0.0f;
#pragma unroll
    for (int k = 0; k < KNN; ++k) {
        const float wk = w[k] * winv;
        acc_c += wk * codes[(size_t)idx[k] * CDIM + lane];
        const float* p = shc + (size_t)idx[k] * (CDIM * SHB) + lane * SHB;
        acc_s += wk * (sm0 * p[0] + sm1 * p[1] + sm2 * p[2]
                     + sm3 * p[3] + sm4 * p[4] + sm5 * p[5]
                     + sm6 * p[6] + sm7 * p[7] + sm8 * p[8]);
    }
    out[n * CDIM + lane] = acc_c;
    out[(size_t)NPTS * CDIM + n * CDIM + lane] = acc_s;
}

extern "C" void kernel_launch(void* const* d_in, const int* in_sizes, int n_in,
                              void* d_out, int out_size, void* d_ws, size_t ws_size,
                              hipStream_t stream) {
    const float* qp    = (const float*)d_in[0];
    const float* vd    = (const float*)d_in[1];
    const float* cpos  = (const float*)d_in[2];
    const float* codes = (const float*)d_in[3];
    const float* shc   = (const float*)d_in[4];
    const int*   knn   = (const int*)d_in[6];
    float* out = (float*)d_out;

    const size_t recA_bytes = (size_t)NCODES * 256 * 4;  // 8 MB
    const size_t recB_bytes = (size_t)NCODES * 64 * 4;   // 2 MB

    if (ws_size >= recA_bytes + recB_bytes) {
        unsigned int* recA = (unsigned int*)d_ws;
        unsigned int* recB = (unsigned int*)((char*)d_ws + recA_bytes);
        hipLaunchKernelGGL(repack_kernel, dim3(NCODES / 4), dim3(256), 0, stream,
                           codes, shc, recA, recB);
        hipLaunchKernelGGL(shcode_phased6, dim3(NBLK), dim3(256), 0, stream,
                           qp, vd, cpos, recA, recB, knn, out);
    } else {
        hipLaunchKernelGGL(shcode_kernel, dim3(NPTS / 4), dim3(256), 0, stream,
                           qp, vd, cpos, codes, shc, knn, out);
    }
}

// Round 11
// 54.517 us; speedup vs baseline: 1.5106x; 1.0600x over previous
//
#include <hip/hip_runtime.h>

#define NPTS   65536
#define KNN    8
#define CDIM   64
#define SHB    9
#define NCODES 8192
#define NPHASE 4
#define PSHIFT 11   // 2048 codes/slice -> 2.6 MB slice fits 4 MB per-XCD L2
#define PTSW   8    // points per wave
#define WAVES  4
#define NBLK   (NPTS / (PTSW * WAVES))   // 2048 blocks -> 8 blocks/CU
#define WSTRIDE 800 // LDS/wave: entries 64x8B @0, pts 8x32B @512, ends 32B @768

typedef _Float16 half2v __attribute__((ext_vector_type(2)));

static __device__ __forceinline__ unsigned int pk16(float a, float b) {
    union { unsigned int u; _Float16 h[2]; } x;
    x.h[0] = (_Float16)a; x.h[1] = (_Float16)b;
    return x.u;
}
static __device__ __forceinline__ half2v as_h2(unsigned int u) {
    union { unsigned int u; half2v h; } x; x.u = u; return x.h;
}

#if defined(__has_builtin)
#if __has_builtin(__builtin_amdgcn_fdot2)
#define HAS_FDOT2 1
#endif
#endif

// recA: (8192, 64dims) x 16 B -> (s0,s1)(s2,s3)(s4,s5)(s6,s7) fp16 pairs.
// recB: (8192, 64dims) x  4 B -> (s8, code) fp16 pair.

__global__ __launch_bounds__(256) void repack_kernel(
    const float* __restrict__ codes,   // (8192,64)
    const float* __restrict__ shc,     // (8192,576)
    unsigned int* __restrict__ recA,   // 8192*256 dwords (8 MB)
    unsigned int* __restrict__ recB)   // 8192*64 dwords (2 MB)
{
    const int wid  = threadIdx.x >> 6;
    const int lane = threadIdx.x & 63;   // dim
    const int c    = blockIdx.x * 4 + wid;

    const float* p = shc + (size_t)c * (CDIM * SHB) + lane * SHB;
    float v[SHB];
#pragma unroll
    for (int s = 0; s < SHB; ++s) v[s] = p[s];
    const float cv = codes[c * CDIM + lane];

    uint4 a;
    a.x = pk16(v[0], v[1]);
    a.y = pk16(v[2], v[3]);
    a.z = pk16(v[4], v[5]);
    a.w = pk16(v[6], v[7]);
    *reinterpret_cast<uint4*>(recA + (size_t)c * 256 + 4 * lane) = a;
    recB[(size_t)c * 64 + lane] = pk16(v[8], cv);
}

// Phased gather kernel with BUILD-TIME visit sorting:
//  - precompute sorts each wave's 64 visits by (phase, point) into a dense
//    LDS entry array (entry = {id, wbar} 8B) via shuffle prefix-sums;
//  - phase loop walks a contiguous entry range: static per-point acc,
//    continuous depth-2 prefetch ACROSS point boundaries (1 prime/phase),
//    no ctz/mask/readfirstlane in the hot loop.
__global__ __launch_bounds__(256) void shcode_phased7(
    const float* __restrict__ qp,
    const float* __restrict__ vd,
    const float* __restrict__ cpos,
    const unsigned int* __restrict__ recA,
    const unsigned int* __restrict__ recB,
    const int*   __restrict__ knn,
    float* __restrict__ out)
{
    __shared__ unsigned char lds[WAVES * WSTRIDE];   // 3200 B

    const int tid   = threadIdx.x;
    const int lane  = tid & 63;
    const int wid   = tid >> 6;
    const int pbase = (blockIdx.x * WAVES + wid) * PTSW;

    unsigned char* wb   = lds + wid * WSTRIDE;
    unsigned int*  entb = (unsigned int*)wb;          // 64 x {id u32, w f32}
    unsigned char* ptsb = wb + 512;                   // 8 x {smh u32[4], s8 f32, pad}
    unsigned char* endsb = wb + 768;                  // 4 phases x 8 u8 ends

    // ---- build: lane l (< PTSW) owns point pbase+l ----
    unsigned cnt4 = 0;          // per-phase visit counts, packed bytes
    int   ids[KNN];
    float wbar[KNN];
    if (lane < PTSW) {
        const int n = pbase + lane;
        const float qx = qp[n * 3 + 0];
        const float qy = qp[n * 3 + 1];
        const float qz = qp[n * 3 + 2];
        float w[KNN];
        float wsum = 0.0f;
#pragma unroll
        for (int k = 0; k < KNN; ++k) {
            const int id = knn[n * KNN + k];
            ids[k] = id;
            const float dx = qx - cpos[id * 3 + 0];
            const float dy = qy - cpos[id * 3 + 1];
            const float dz = qz - cpos[id * 3 + 2];
            w[k] = 1.0f / (dx * dx + dy * dy + dz * dz + 1e-16f);
            wsum += w[k];
        }
        const float inv = 1.0f / wsum;
#pragma unroll
        for (int k = 0; k < KNN; ++k) {
            wbar[k] = w[k] * inv;
            cnt4 += 1u << (8 * ((unsigned)ids[k] >> PSHIFT));
        }
        // per-point SH block
        const float x = vd[n * 3 + 0];
        const float y = vd[n * 3 + 1];
        const float z = vd[n * 3 + 2];
        const float xx = x * x, yy = y * y, zz = z * z;
        uint4 SM;
        SM.x = pk16(0.28209479177387814f,           -0.4886025119029199f * y);
        SM.y = pk16(0.4886025119029199f * z,        -0.4886025119029199f * x);
        SM.z = pk16(1.0925484305920792f * (x * y),  -1.0925484305920792f * (y * z));
        SM.w = pk16(0.31539156525252005f * (2.0f * zz - xx - yy),
                    -1.0925484305920792f * (x * z));
        *(uint4*)(ptsb + lane * 32) = SM;
        *(float*)(ptsb + lane * 32 + 16) = 0.5462742152960396f * (xx - yy);
    }

    // ---- shuffle prefix-sums over the wave's 8 points (bytewise packed) ----
    unsigned pref = 0, tot4 = 0;
#pragma unroll
    for (int p = 0; p < PTSW; ++p) {
        const unsigned c = (unsigned)__shfl((int)cnt4, p);   // from lanes 0..7
        tot4 += c;
        if (p < lane) pref += c;
    }
    const unsigned tot = (unsigned)__builtin_amdgcn_readfirstlane((int)tot4);
    const int b1 = (int)(tot & 0xffu);
    const int b2 = b1 + (int)((tot >> 8) & 0xffu);
    const int b3 = b2 + (int)((tot >> 16) & 0xffu);
    const unsigned bpack = ((unsigned)b1 << 8) | ((unsigned)b2 << 16) |
                           ((unsigned)b3 << 24);             // base(ph) bytes, base0=0

    if (lane < PTSW) {
        // per-(phase,point) end offsets
#pragma unroll
        for (int f = 0; f < NPHASE; ++f) {
            const unsigned basef = (bpack >> (8 * f)) & 0xffu;
            const unsigned off   = (pref  >> (8 * f)) & 0xffu;
            const unsigned cc    = (cnt4  >> (8 * f)) & 0xffu;
            endsb[f * 8 + lane] = (unsigned char)(basef + off + cc);
        }
        // scatter entries sorted by (phase, point)
        unsigned r4 = 0;
#pragma unroll
        for (int k = 0; k < KNN; ++k) {
            const unsigned f = (unsigned)ids[k] >> PSHIFT;
            const unsigned idx = ((bpack >> (8 * f)) & 0xffu)
                               + ((pref  >> (8 * f)) & 0xffu)
                               + ((r4    >> (8 * f)) & 0xffu);
            r4 += 1u << (8 * f);
            entb[idx * 2 + 0] = (unsigned)ids[k];
            entb[idx * 2 + 1] = __float_as_uint(wbar[k]);
        }
    }
    __syncthreads();

    float acc_c[PTSW], acc_s[PTSW];
#pragma unroll
    for (int p = 0; p < PTSW; ++p) { acc_c[p] = 0.0f; acc_s[p] = 0.0f; }

#pragma unroll
    for (int ph = 0; ph < NPHASE; ++ph) {
        const int ibeg  = (ph == 0) ? 0  : ((ph == 1) ? b1 : ((ph == 2) ? b2 : b3));
        const int iendc = (ph == 0) ? b1 : ((ph == 1) ? b2 : ((ph == 2) ? b3 : 64));

        if (ibeg < iendc) {                     // wave-uniform
            // per-point end offsets for this phase -> scalars
            const unsigned pe0 = *(const unsigned*)(endsb + ph * 8);
            const unsigned pe1 = *(const unsigned*)(endsb + ph * 8 + 4);
            const int se0 = __builtin_amdgcn_readfirstlane((int)pe0);
            const int se1 = __builtin_amdgcn_readfirstlane((int)pe1);

            int i = ibeg;
            // ---- prime visit ibeg ----
            uint2 E = *(const uint2*)(entb + i * 2);         // uniform ds_read_b64
            uint4 A = *(const uint4*)(recA + (size_t)E.x * 256 + 4 * lane);
            unsigned B = recB[E.x * 64 + lane];

#pragma unroll
            for (int p = 0; p < PTSW; ++p) {
                const int pend = ((p < 4 ? se0 : se1) >> (8 * (p & 3))) & 0xff;
                if (i >= pend) continue;        // uniform

                const uint4 SM = *(const uint4*)(ptsb + p * 32);
                const float s8m = *(const float*)(ptsb + p * 32 + 16);
                const half2v sh0 = as_h2(SM.x), sh1 = as_h2(SM.y);
                const half2v sh2 = as_h2(SM.z), sh3 = as_h2(SM.w);

                while (i < pend) {
                    // prefetch next visit (cross-point-boundary pipeline)
                    uint2 E2 = {0u, 0u}; uint4 A2 = {0u,0u,0u,0u}; unsigned B2 = 0u;
                    if (i + 1 < iendc) {        // uniform
                        E2 = *(const uint2*)(entb + (i + 1) * 2);
                        A2 = *(const uint4*)(recA + (size_t)E2.x * 256 + 4 * lane);
                        B2 = recB[E2.x * 64 + lane];
                    }
                    // consume current into static acc[p]
                    {
                        const half2v bb = as_h2(B);
                        const float f8 = (float)bb[0];
                        const float fc = (float)bb[1];
                        const float wk = __uint_as_float(E.y);
#ifdef HAS_FDOT2
                        float dot = s8m * f8;
                        dot = __builtin_amdgcn_fdot2(as_h2(A.w), sh3, dot, false);
                        dot = __builtin_amdgcn_fdot2(as_h2(A.z), sh2, dot, false);
                        dot = __builtin_amdgcn_fdot2(as_h2(A.y), sh1, dot, false);
                        dot = __builtin_amdgcn_fdot2(as_h2(A.x), sh0, dot, false);
#else
                        const half2v a0 = as_h2(A.x), a1 = as_h2(A.y);
                        const half2v a2 = as_h2(A.z), a3 = as_h2(A.w);
                        float dot = s8m * f8;
                        dot += (float)a0[0]*(float)sh0[0] + (float)a0[1]*(float)sh0[1];
                        dot += (float)a1[0]*(float)sh1[0] + (float)a1[1]*(float)sh1[1];
                        dot += (float)a2[0]*(float)sh2[0] + (float)a2[1]*(float)sh2[1];
                        dot += (float)a3[0]*(float)sh3[0] + (float)a3[1]*(float)sh3[1];
#endif
                        acc_s[p] = fmaf(wk, dot, acc_s[p]);
                        acc_c[p] = fmaf(wk, fc,  acc_c[p]);
                    }
                    E = E2; A = A2; B = B2;
                    ++i;
                }
            }
        }
        __syncthreads();   // keep block's waves phase-aligned
    }

#pragma unroll
    for (int p = 0; p < PTSW; ++p) {
        const int n = pbase + p;
        __builtin_nontemporal_store(acc_c[p], &out[n * CDIM + lane]);
        __builtin_nontemporal_store(acc_s[p],
                                    &out[(size_t)NPTS * CDIM + n * CDIM + lane]);
    }
}

// --- fallback (round-1 fp32 direct-gather) if workspace too small ---
__global__ __launch_bounds__(256) void shcode_kernel(
    const float* __restrict__ qp, const float* __restrict__ vd,
    const float* __restrict__ cpos, const float* __restrict__ codes,
    const float* __restrict__ shc, const int* __restrict__ knn,
    float* __restrict__ out)
{
    const int wid  = threadIdx.x >> 6;
    const int lane = threadIdx.x & 63;
    const int n    = blockIdx.x * 4 + wid;

    const float x = vd[n * 3 + 0], y = vd[n * 3 + 1], z = vd[n * 3 + 2];
    const float xx = x * x, yy = y * y, zz = z * z;
    const float sm0 = 0.28209479177387814f;
    const float sm1 = -0.4886025119029199f * y;
    const float sm2 =  0.4886025119029199f * z;
    const float sm3 = -0.4886025119029199f * x;
    const float sm4 =  1.0925484305920792f * (x * y);
    const float sm5 = -1.0925484305920792f * (y * z);
    const float sm6 =  0.31539156525252005f * (2.0f * zz - xx - yy);
    const float sm7 = -1.0925484305920792f * (x * z);
    const float sm8 =  0.5462742152960396f * (xx - yy);

    const float qx = qp[n * 3 + 0], qy = qp[n * 3 + 1], qz = qp[n * 3 + 2];

    int idx[KNN]; float w[KNN]; float wsum = 0.0f;
#pragma unroll
    for (int k = 0; k < KNN; ++k) {
        int id = __builtin_amdgcn_readfirstlane(knn[n * KNN + k]);
        idx[k] = id;
        const float dx = qx - cpos[id * 3 + 0];
        const float dy = qy - cpos[id * 3 + 1];
        const float dz = qz - cpos[id * 3 + 2];
        const float sd = dx * dx + dy * dy + dz * dz + 1e-16f;
        w[k] = 1.0f / sd; wsum += w[k];
    }
    const float winv = 1.0f / wsum;

    float acc_c = 0.0f, acc_s = 0.0f;
#pragma unroll
    for (int k = 0; k < KNN; ++k) {
        const float wk = w[k] * winv;
        acc_c += wk * codes[(size_t)idx[k] * CDIM + lane];
        const float* p = shc + (size_t)idx[k] * (CDIM * SHB) + lane * SHB;
        acc_s += wk * (sm0 * p[0] + sm1 * p[1] + sm2 * p[2]
                     + sm3 * p[3] + sm4 * p[4] + sm5 * p[5]
                     + sm6 * p[6] + sm7 * p[7] + sm8 * p[8]);
    }
    out[n * CDIM + lane] = acc_c;
    out[(size_t)NPTS * CDIM + n * CDIM + lane] = acc_s;
}

extern "C" void kernel_launch(void* const* d_in, const int* in_sizes, int n_in,
                              void* d_out, int out_size, void* d_ws, size_t ws_size,
                              hipStream_t stream) {
    const float* qp    = (const float*)d_in[0];
    const float* vd    = (const float*)d_in[1];
    const float* cpos  = (const float*)d_in[2];
    const float* codes = (const float*)d_in[3];
    const float* shc   = (const float*)d_in[4];
    const int*   knn   = (const int*)d_in[6];
    float* out = (float*)d_out;

    const size_t recA_bytes = (size_t)NCODES * 256 * 4;  // 8 MB
    const size_t recB_bytes = (size_t)NCODES * 64 * 4;   // 2 MB

    if (ws_size >= recA_bytes + recB_bytes) {
        unsigned int* recA = (unsigned int*)d_ws;
        unsigned int* recB = (unsigned int*)((char*)d_ws + recA_bytes);
        hipLaunchKernelGGL(repack_kernel, dim3(NCODES / 4), dim3(256), 0, stream,
                           codes, shc, recA, recB);
        hipLaunchKernelGGL(shcode_phased7, dim3(NBLK), dim3(256), 0, stream,
                           qp, vd, cpos, recA, recB, knn, out);
    } else {
        hipLaunchKernelGGL(shcode_kernel, dim3(NPTS / 4), dim3(256), 0, stream,
                           qp, vd, cpos, codes, shc, knn, out);
    }
}

// Round 12
// 51.594 us; speedup vs baseline: 1.5962x; 1.0567x over previous
//
#include <hip/hip_runtime.h>

#define NPTS   65536
#define KNN    8
#define CDIM   64
#define SHB    9
#define NCODES 8192
#define NPHASE 4
#define PSHIFT 11  // 2048 codes/slice -> 2.6 MB slice fits 4 MB per-XCD L2
#define PTSW   8   // points per wave
#define WAVES  4
#define NBLK   (NPTS / (PTSW * WAVES))   // 2048 blocks -> 8 blocks/CU
#define LSTRIDE 80 // per-point LDS: ids u16[8]@0, wbar f32[8]@16, smh u32[4]@48, sm8 f32@64, mask u32@68

typedef _Float16 half2v __attribute__((ext_vector_type(2)));

static __device__ __forceinline__ unsigned int pk16(float a, float b) {
    union { unsigned int u; _Float16 h[2]; } x;
    x.h[0] = (_Float16)a; x.h[1] = (_Float16)b;
    return x.u;
}
static __device__ __forceinline__ half2v as_h2(unsigned int u) {
    union { unsigned int u; half2v h; } x; x.u = u; return x.h;
}

#if defined(__has_builtin)
#if __has_builtin(__builtin_amdgcn_fdot2)
#define HAS_FDOT2 1
#endif
#endif

// recA: (8192, 64dims) x 16 B -> (s0,s1)(s2,s3)(s4,s5)(s6,s7) fp16 pairs,
//       lane-contiguous (wave reads one code's row as a 1024 B burst).
// recB: (8192, 64dims) x  4 B -> (s8, code) fp16 pair.
// Per-visit gather: 1 dwordx4 + 1 dword = the fp16-precision instruction floor.

__global__ __launch_bounds__(256) void repack_kernel(
    const float* __restrict__ codes,   // (8192,64)
    const float* __restrict__ shc,     // (8192,576)
    unsigned int* __restrict__ recA,   // 8192*256 dwords (8 MB)
    unsigned int* __restrict__ recB)   // 8192*64 dwords (2 MB)
{
    const int wid  = threadIdx.x >> 6;
    const int lane = threadIdx.x & 63;   // dim
    const int c    = blockIdx.x * 4 + wid;

    const float* p = shc + (size_t)c * (CDIM * SHB) + lane * SHB;
    float v[SHB];
#pragma unroll
    for (int s = 0; s < SHB; ++s) v[s] = p[s];
    const float cv = codes[c * CDIM + lane];

    uint4 a;
    a.x = pk16(v[0], v[1]);
    a.y = pk16(v[2], v[3]);
    a.z = pk16(v[4], v[5]);
    a.w = pk16(v[6], v[7]);
    *reinterpret_cast<uint4*>(recA + (size_t)c * 256 + 4 * lane) = a;
    recB[(size_t)c * 64 + lane] = pk16(v[8], cv);
}

// Phased gather kernel (R6 structure — measured best of 7 structural
// variants; R10 dual-stream and R11 sorted-pipeline both failed to beat it,
// confirming the residual is VMEM-issue + VALU, not exposed latency).
__global__ __launch_bounds__(256) void shcode_phased3(
    const float* __restrict__ qp,
    const float* __restrict__ vd,
    const float* __restrict__ cpos,
    const unsigned int* __restrict__ recA,
    const unsigned int* __restrict__ recB,
    const int*   __restrict__ knn,
    float* __restrict__ out)
{
    __shared__ unsigned char lds[WAVES * PTSW * LSTRIDE];   // 2560 B

    const int tid   = threadIdx.x;
    const int lane  = tid & 63;
    const int wid   = tid >> 6;
    const int pbase = (blockIdx.x * WAVES + wid) * PTSW;

    // ---- precompute: lane l (< PTSW) owns point pbase+l ----
    if (lane < PTSW) {
        const int n = pbase + lane;
        unsigned char* pr = lds + (wid * PTSW + lane) * LSTRIDE;
        unsigned short* ids16 = (unsigned short*)(pr + 0);
        float*          wbar  = (float*)(pr + 16);
        unsigned int*   smh   = (unsigned int*)(pr + 48);
        float*          sm8p  = (float*)(pr + 64);
        unsigned int*   maskp = (unsigned int*)(pr + 68);

        const float qx = qp[n * 3 + 0];
        const float qy = qp[n * 3 + 1];
        const float qz = qp[n * 3 + 2];

        int   ids[KNN];
        float w[KNN];
        float wsum = 0.0f;
#pragma unroll
        for (int k = 0; k < KNN; ++k) {
            const int id = knn[n * KNN + k];
            ids[k] = id;
            const float dx = qx - cpos[id * 3 + 0];
            const float dy = qy - cpos[id * 3 + 1];
            const float dz = qz - cpos[id * 3 + 2];
            w[k] = 1.0f / (dx * dx + dy * dy + dz * dz + 1e-16f);
            wsum += w[k];
        }
        const float inv = 1.0f / wsum;
        unsigned int mask = 0u;
#pragma unroll
        for (int k = 0; k < KNN; ++k) {
            ids16[k] = (unsigned short)ids[k];
            wbar[k]  = w[k] * inv;
            mask |= 1u << (((unsigned)ids[k] >> PSHIFT) * 8 + k);
        }
        *maskp = mask;

        const float x = vd[n * 3 + 0];
        const float y = vd[n * 3 + 1];
        const float z = vd[n * 3 + 2];
        const float xx = x * x, yy = y * y, zz = z * z;
        smh[0] = pk16(0.28209479177387814f,           -0.4886025119029199f * y);
        smh[1] = pk16(0.4886025119029199f * z,        -0.4886025119029199f * x);
        smh[2] = pk16(1.0925484305920792f * (x * y),  -1.0925484305920792f * (y * z));
        smh[3] = pk16(0.31539156525252005f * (2.0f * zz - xx - yy),
                      -1.0925484305920792f * (x * z));
        *sm8p  = 0.5462742152960396f * (xx - yy);
    }
    __syncthreads();

    float acc_c[PTSW], acc_s[PTSW];
#pragma unroll
    for (int p = 0; p < PTSW; ++p) { acc_c[p] = 0.0f; acc_s[p] = 0.0f; }

    for (int ph = 0; ph < NPHASE; ++ph) {
#pragma unroll
        for (int p = 0; p < PTSW; ++p) {
            const unsigned char* pr = lds + (wid * PTSW + p) * LSTRIDE;
            unsigned int m8 =
                ((unsigned int)__builtin_amdgcn_readfirstlane(
                     (int)*(const unsigned int*)(pr + 68)) >> (8 * ph)) & 0xffu;
            if (!m8) continue;                      // uniform scalar branch

            const unsigned int* smu = (const unsigned int*)(pr + 48);
            const half2v smh0 = as_h2(smu[0]);
            const half2v smh1 = as_h2(smu[1]);
            const half2v smh2 = as_h2(smu[2]);
            const half2v smh3 = as_h2(smu[3]);
            const float  sm8f = *(const float*)(pr + 64);

            while (m8) {
                const int k = __builtin_ctz(m8);
                m8 &= m8 - 1u;
                const int id = __builtin_amdgcn_readfirstlane(
                    (int)((const unsigned short*)pr)[k]);
                const float wk = ((const float*)(pr + 16))[k];

                const uint4 A = *reinterpret_cast<const uint4*>(
                    recA + (size_t)id * 256 + 4 * lane);
                const unsigned int B = recB[(size_t)id * 64 + lane];

                const half2v b2 = as_h2(B);
                const float f8 = (float)b2[0];
                const float fc = (float)b2[1];

#ifdef HAS_FDOT2
                float agg = sm8f * f8;
                agg = __builtin_amdgcn_fdot2(as_h2(A.w), smh3, agg, false);
                agg = __builtin_amdgcn_fdot2(as_h2(A.z), smh2, agg, false);
                agg = __builtin_amdgcn_fdot2(as_h2(A.y), smh1, agg, false);
                agg = __builtin_amdgcn_fdot2(as_h2(A.x), smh0, agg, false);
#else
                const half2v a0 = as_h2(A.x), a1 = as_h2(A.y);
                const half2v a2 = as_h2(A.z), a3 = as_h2(A.w);
                float agg = sm8f * f8;
                agg += (float)a0[0] * (float)smh0[0] + (float)a0[1] * (float)smh0[1];
                agg += (float)a1[0] * (float)smh1[0] + (float)a1[1] * (float)smh1[1];
                agg += (float)a2[0] * (float)smh2[0] + (float)a2[1] * (float)smh2[1];
                agg += (float)a3[0] * (float)smh3[0] + (float)a3[1] * (float)smh3[1];
#endif
                acc_s[p] += wk * agg;
                acc_c[p] += wk * fc;
            }
        }
        if (ph != NPHASE - 1)
            __syncthreads();   // keep block's waves phase-aligned (last one redundant)
    }

#pragma unroll
    for (int p = 0; p < PTSW; ++p) {
        const int n = pbase + p;
        __builtin_nontemporal_store(acc_c[p], &out[n * CDIM + lane]);
        __builtin_nontemporal_store(acc_s[p],
                                    &out[(size_t)NPTS * CDIM + n * CDIM + lane]);
    }
}

// --- fallback (round-1 fp32 direct-gather) if workspace too small ---
__global__ __launch_bounds__(256) void shcode_kernel(
    const float* __restrict__ qp, const float* __restrict__ vd,
    const float* __restrict__ cpos, const float* __restrict__ codes,
    const float* __restrict__ shc, const int* __restrict__ knn,
    float* __restrict__ out)
{
    const int wid  = threadIdx.x >> 6;
    const int lane = threadIdx.x & 63;
    const int n    = blockIdx.x * 4 + wid;

    const float x = vd[n * 3 + 0], y = vd[n * 3 + 1], z = vd[n * 3 + 2];
    const float xx = x * x, yy = y * y, zz = z * z;
    const float sm0 = 0.28209479177387814f;
    const float sm1 = -0.4886025119029199f * y;
    const float sm2 =  0.4886025119029199f * z;
    const float sm3 = -0.4886025119029199f * x;
    const float sm4 =  1.0925484305920792f * (x * y);
    const float sm5 = -1.0925484305920792f * (y * z);
    const float sm6 =  0.31539156525252005f * (2.0f * zz - xx - yy);
    const float sm7 = -1.0925484305920792f * (x * z);
    const float sm8 =  0.5462742152960396f * (xx - yy);

    const float qx = qp[n * 3 + 0], qy = qp[n * 3 + 1], qz = qp[n * 3 + 2];

    int idx[KNN]; float w[KNN]; float wsum = 0.0f;
#pragma unroll
    for (int k = 0; k < KNN; ++k) {
        int id = __builtin_amdgcn_readfirstlane(knn[n * KNN + k]);
        idx[k] = id;
        const float dx = qx - cpos[id * 3 + 0];
        const float dy = qy - cpos[id * 3 + 1];
        const float dz = qz - cpos[id * 3 + 2];
        const float sd = dx * dx + dy * dy + dz * dz + 1e-16f;
        w[k] = 1.0f / sd; wsum += w[k];
    }
    const float winv = 1.0f / wsum;

    float acc_c = 0.0f, acc_s = 0.0f;
#pragma unroll
    for (int k = 0; k < KNN; ++k) {
        const float wk = w[k] * winv;
        acc_c += wk * codes[(size_t)idx[k] * CDIM + lane];
        const float* p = shc + (size_t)idx[k] * (CDIM * SHB) + lane * SHB;
        acc_s += wk * (sm0 * p[0] + sm1 * p[1] + sm2 * p[2]
                     + sm3 * p[3] + sm4 * p[4] + sm5 * p[5]
                     + sm6 * p[6] + sm7 * p[7] + sm8 * p[8]);
    }
    out[n * CDIM + lane] = acc_c;
    out[(size_t)NPTS * CDIM + n * CDIM + lane] = acc_s;
}

extern "C" void kernel_launch(void* const* d_in, const int* in_sizes, int n_in,
                              void* d_out, int out_size, void* d_ws, size_t ws_size,
                              hipStream_t stream) {
    const float* qp    = (const float*)d_in[0];
    const float* vd    = (const float*)d_in[1];
    const float* cpos  = (const float*)d_in[2];
    const float* codes = (const float*)d_in[3];
    const float* shc   = (const float*)d_in[4];
    const int*   knn   = (const int*)d_in[6];
    float* out = (float*)d_out;

    const size_t recA_bytes = (size_t)NCODES * 256 * 4;  // 8 MB
    const size_t recB_bytes = (size_t)NCODES * 64 * 4;   // 2 MB

    if (ws_size >= recA_bytes + recB_bytes) {
        unsigned int* recA = (unsigned int*)d_ws;
        unsigned int* recB = (unsigned int*)((char*)d_ws + recA_bytes);
        hipLaunchKernelGGL(repack_kernel, dim3(NCODES / 4), dim3(256), 0, stream,
                           codes, shc, recA, recB);
        hipLaunchKernelGGL(shcode_phased3, dim3(NBLK), dim3(256), 0, stream,
                           qp, vd, cpos, recA, recB, knn, out);
    } else {
        hipLaunchKernelGGL(shcode_kernel, dim3(NPTS / 4), dim3(256), 0, stream,
                           qp, vd, cpos, codes, shc, knn, out);
    }
}